// Round 1
// baseline (601.959 us; speedup 1.0000x reference)
//
#include <hip/hip_runtime.h>
#include <math.h>

#define N_ROWS 2048
#define D_IN 256
#define D_HID 32
#define D_OUT 256

__device__ __forceinline__ float sigmoidf_(float v) {
    return 1.0f / (1.0f + expf(-v));
}

// One block (256 threads) per row: att = tanh(row @ w1 + b1) @ w2 + b2
// Grid: 4096 blocks; first 2048 -> x/ax weights, next 2048 -> neibs/an weights.
__global__ __launch_bounds__(256) void att_mlp_kernel(
    const float* __restrict__ x, const float* __restrict__ neibs,
    const float* __restrict__ ax_w1, const float* __restrict__ ax_b1,
    const float* __restrict__ ax_w2, const float* __restrict__ ax_b2,
    const float* __restrict__ an_w1, const float* __restrict__ an_b1,
    const float* __restrict__ an_w2, const float* __restrict__ an_b2,
    float* __restrict__ x_att, float* __restrict__ n_att)
{
    const int tid = threadIdx.x;
    const bool is_x = (blockIdx.x < N_ROWS);
    const int row = is_x ? blockIdx.x : (blockIdx.x - N_ROWS);

    const float* __restrict__ in = is_x ? x : neibs;
    const float* __restrict__ w1 = is_x ? ax_w1 : an_w1;
    const float* __restrict__ b1 = is_x ? ax_b1 : an_b1;
    const float* __restrict__ w2 = is_x ? ax_w2 : an_w2;
    const float* __restrict__ b2 = is_x ? ax_b2 : an_b2;
    float* __restrict__ outp = is_x ? x_att : n_att;

    __shared__ float srow[D_IN];
    __shared__ float red[256];
    __shared__ float h[D_HID];

    srow[tid] = in[row * D_IN + tid];
    __syncthreads();

    // Layer 1: 32 output cols, K=256 split across 8 chunks of 32.
    const int c = tid & 31;        // output column
    const int chunk = tid >> 5;    // k-chunk 0..7
    float partial = 0.0f;
    const int k0 = chunk * 32;
#pragma unroll
    for (int kk = 0; kk < 32; ++kk) {
        const int k = k0 + kk;
        partial += srow[k] * w1[k * D_HID + c];
    }
    red[tid] = partial;
    __syncthreads();

    if (tid < D_HID) {
        float s = b1[tid];
#pragma unroll
        for (int j = 0; j < 8; ++j) s += red[j * 32 + tid];
        h[tid] = tanhf(s);
    }
    __syncthreads();

    // Layer 2: 32x32
    if (tid < D_HID) {
        float s = b2[tid];
#pragma unroll
        for (int j = 0; j < D_HID; ++j) s += h[j] * w2[j * D_HID + tid];
        outp[row * D_HID + tid] = s;
    }
}

// One block (256 threads) per target row n:
//   s[m] = dot32(x_att[n], n_att[m]) * mask[n,m]; p = softmax(s)
//   agg[d] = sigmoid(sum_m p[m] * neibs[m,d])
//   out[n,o] = sigmoid(x[n,:] @ W[0:256,o] + agg @ W[256:512,o] + b[o])
__global__ __launch_bounds__(256) void attn_agg_kernel(
    const float* __restrict__ x, const float* __restrict__ neibs,
    const float* __restrict__ mask,
    const float* __restrict__ x_att, const float* __restrict__ n_att,
    const float* __restrict__ fcx_w, const float* __restrict__ fcx_b,
    float* __restrict__ out)
{
    const int n = blockIdx.x;
    const int tid = threadIdx.x;

    __shared__ float xa[D_HID];
    __shared__ float p[N_ROWS];     // scores -> probabilities (8 KB)
    __shared__ float red[256];
    __shared__ float agg[D_IN];
    __shared__ float xrow[D_IN];

    if (tid < D_HID) xa[tid] = x_att[n * D_HID + tid];
    xrow[tid] = x[n * D_IN + tid];
    __syncthreads();

    // Scores + local max
    float lmax = -INFINITY;
    for (int m = tid; m < N_ROWS; m += 256) {
        const float* na = n_att + m * D_HID;
        float s = 0.0f;
#pragma unroll
        for (int hh = 0; hh < D_HID; ++hh) s += xa[hh] * na[hh];
        s *= mask[n * (size_t)N_ROWS + m];
        p[m] = s;
        lmax = fmaxf(lmax, s);
    }
    red[tid] = lmax;
    __syncthreads();
#pragma unroll
    for (int off = 128; off > 0; off >>= 1) {
        if (tid < off) red[tid] = fmaxf(red[tid], red[tid + off]);
        __syncthreads();
    }
    const float gmax = red[0];
    __syncthreads();

    // exp + local sum
    float lsum = 0.0f;
    for (int m = tid; m < N_ROWS; m += 256) {
        const float e = expf(p[m] - gmax);
        p[m] = e;
        lsum += e;
    }
    red[tid] = lsum;
    __syncthreads();
#pragma unroll
    for (int off = 128; off > 0; off >>= 1) {
        if (tid < off) red[tid] += red[tid + off];
        __syncthreads();
    }
    const float inv = 1.0f / red[0];
    __syncthreads();

    // agg[d] for d = tid: sum over all m. p[m] broadcast from LDS, neibs coalesced.
    float acc = 0.0f;
    for (int m = 0; m < N_ROWS; ++m) {
        acc += p[m] * neibs[m * (size_t)D_IN + tid];
    }
    agg[tid] = sigmoidf_(acc * inv);
    __syncthreads();

    // Output GEMV: o = tid
    float o = fcx_b[tid];
#pragma unroll 4
    for (int k = 0; k < D_IN; ++k) {
        o += xrow[k] * fcx_w[k * (size_t)D_OUT + tid];
    }
#pragma unroll 4
    for (int k = 0; k < D_IN; ++k) {
        o += agg[k] * fcx_w[(D_IN + k) * (size_t)D_OUT + tid];
    }
    out[n * (size_t)D_OUT + tid] = sigmoidf_(o);
}

extern "C" void kernel_launch(void* const* d_in, const int* in_sizes, int n_in,
                              void* d_out, int out_size, void* d_ws, size_t ws_size,
                              hipStream_t stream) {
    const float* x      = (const float*)d_in[0];
    const float* neibs  = (const float*)d_in[1];
    // d_in[2] = edge_emb: dead code in the reference, intentionally unread.
    const float* mask   = (const float*)d_in[3];
    const float* ax_w1  = (const float*)d_in[4];
    const float* ax_b1  = (const float*)d_in[5];
    const float* ax_w2  = (const float*)d_in[6];
    const float* ax_b2  = (const float*)d_in[7];
    const float* an_w1  = (const float*)d_in[8];
    const float* an_b1  = (const float*)d_in[9];
    const float* an_w2  = (const float*)d_in[10];
    const float* an_b2  = (const float*)d_in[11];
    // d_in[12..15] = ae_* : dead code, unread.
    const float* fcx_w  = (const float*)d_in[16];
    const float* fcx_b  = (const float*)d_in[17];
    float* out = (float*)d_out;

    float* x_att = (float*)d_ws;                       // 2048*32 floats
    float* n_att = x_att + (size_t)N_ROWS * D_HID;     // 2048*32 floats

    att_mlp_kernel<<<2 * N_ROWS, 256, 0, stream>>>(
        x, neibs, ax_w1, ax_b1, ax_w2, ax_b2,
        an_w1, an_b1, an_w2, an_b2, x_att, n_att);

    attn_agg_kernel<<<N_ROWS, 256, 0, stream>>>(
        x, neibs, mask, x_att, n_att, fcx_w, fcx_b, out);
}

// Round 2
// 444.830 us; speedup vs baseline: 1.3532x; 1.3532x over previous
//
#include <hip/hip_runtime.h>
#include <hip/hip_bf16.h>
#include <math.h>

#define NROWS 2048
#define DIN 256
#define DH 32
#define DOUT 256

typedef unsigned short ushort_t;
typedef unsigned int uint_t;

__device__ __forceinline__ float bf2f(uint_t u) {      // low 16 bits as bf16
    union { uint_t i; float f; } v; v.i = u << 16; return v.f;
}
__device__ __forceinline__ float bfhi2f(uint_t u) {    // high 16 bits as bf16
    union { uint_t i; float f; } v; v.i = u & 0xffff0000u; return v.f;
}
__device__ __forceinline__ ushort_t f2bf(float f) {    // RN via hip intrinsic
    __hip_bfloat16 h = __float2bfloat16(f);
    union { __hip_bfloat16 h; ushort_t u; } v; v.h = h; return v.u;
}
__device__ __forceinline__ float sigm(float v) { return 1.0f / (1.0f + __expf(-v)); }

// ---------------- Kernel 1: the two tiny MLPs ----------------
// 512 blocks x 256 threads; block handles 8 rows; group of 32 threads per row.
// First 256 blocks: x -> x_att (fp32). Next 256: neibs -> n_att (bf16).
__global__ __launch_bounds__(256) void mlp_kernel(
    const float* __restrict__ x, const float* __restrict__ neibs,
    const float* __restrict__ ax_w1, const float* __restrict__ ax_b1,
    const float* __restrict__ ax_w2, const float* __restrict__ ax_b2,
    const float* __restrict__ an_w1, const float* __restrict__ an_b1,
    const float* __restrict__ an_w2, const float* __restrict__ an_b2,
    float* __restrict__ x_att, ushort_t* __restrict__ n_att)
{
    const int t = threadIdx.x;
    const bool is_x = blockIdx.x < 256;
    const int row0 = (is_x ? blockIdx.x : blockIdx.x - 256) * 8;
    const float* __restrict__ in = is_x ? x : neibs;
    const float* __restrict__ w1 = is_x ? ax_w1 : an_w1;
    const float* __restrict__ b1 = is_x ? ax_b1 : an_b1;
    const float* __restrict__ w2 = is_x ? ax_w2 : an_w2;
    const float* __restrict__ b2 = is_x ? ax_b2 : an_b2;

    __shared__ float srow[8][DIN];
    __shared__ float hbuf[8][DH];

    const int r = t >> 5, c = t & 31;
    {
        const float4* in4 = (const float4*)(in + (row0 + r) * DIN);
        float4 a = in4[c * 2], b = in4[c * 2 + 1];
        *(float4*)&srow[r][c * 8] = a;
        *(float4*)&srow[r][c * 8 + 4] = b;
    }
    __syncthreads();

    float s = b1[c];
#pragma unroll 8
    for (int k = 0; k < DIN; ++k) s += srow[r][k] * w1[k * DH + c];
    s = tanhf(s);
    hbuf[r][c] = s;
    __syncthreads();

    float s2 = b2[c];
#pragma unroll
    for (int j = 0; j < DH; ++j) s2 += hbuf[r][j] * w2[j * DH + c];

    if (is_x) x_att[(row0 + r) * DH + c] = s2;
    else      n_att[(row0 + r) * DH + c] = f2bf(s2);
}

// 3-round split-K tree reduction of per-thread acc[8][8] across the 8 kc groups.
// red has 8192 floats (reuses pT). Conflict-free: addr stride 32 floats per i.
__device__ __forceinline__ void block_reduce_acc(float* red, int kc, int dg,
                                                 float (&acc)[8][8])
{
#pragma unroll
    for (int half = 4; half >= 1; half >>= 1) {
        __syncthreads();
        if (kc >= half && kc < 2 * half) {
            const int slot = kc - half;
#pragma unroll
            for (int i = 0; i < 64; ++i)
                red[slot * 2048 + i * 32 + dg] = acc[i >> 3][i & 7];
        }
        __syncthreads();
        if (kc < half) {
#pragma unroll
            for (int i = 0; i < 64; ++i)
                acc[i >> 3][i & 7] += red[kc * 2048 + i * 32 + dg];
        }
    }
}

// ---------------- Kernel 2: fused scores/softmax/PV/FC ----------------
// 256 blocks x 256 threads; block handles 8 target rows.
__global__ __launch_bounds__(256) void attn_kernel(
    const float* __restrict__ x, const float* __restrict__ neibs,
    const float* __restrict__ mask,
    const float* __restrict__ x_att, const ushort_t* __restrict__ n_att,
    const float* __restrict__ fcx_w, const float* __restrict__ fcx_b,
    float* __restrict__ out)
{
    __shared__ ushort_t pT[NROWS * 8];   // 32 KB: probs, transposed [m][r], bf16
    __shared__ ushort_t AT[512 * 8];     // 8 KB: concat(x,agg) transposed [k][r], bf16
    __shared__ float row_inv[8];

    const int t = threadIdx.x;
    const int n0 = blockIdx.x * 8;

    // ---- Phase 0: stage x into AT[k][r] (k = t, 0..255) ----
    {
        uint4 q;
        uint_t pk[4];
#pragma unroll
        for (int rp = 0; rp < 4; ++rp) {
            float v0 = x[(n0 + 2 * rp) * DIN + t];
            float v1 = x[(n0 + 2 * rp + 1) * DIN + t];
            pk[rp] = (uint_t)f2bf(v0) | ((uint_t)f2bf(v1) << 16);
        }
        q.x = pk[0]; q.y = pk[1]; q.z = pk[2]; q.w = pk[3];
        *(uint4*)&AT[t * 8] = q;
    }

    // ---- Phase 1: scores. Wave wv owns rows r0=2wv, r1=2wv+1; lanes cover m ----
    const int wv = t >> 6, lane = t & 63;
    const int r0 = 2 * wv, r1 = r0 + 1;
    float xa0[DH], xa1[DH];
#pragma unroll
    for (int h = 0; h < DH; ++h) {
        xa0[h] = x_att[(n0 + r0) * DH + h];
        xa1[h] = x_att[(n0 + r1) * DH + h];
    }
    float mx0 = -1e30f, mx1 = -1e30f;
    const uint4* na4 = (const uint4*)n_att;
    for (int it = 0; it < 32; ++it) {
        const int m = it * 64 + lane;
        float s0 = 0.f, s1 = 0.f;
#pragma unroll
        for (int q = 0; q < 4; ++q) {
            uint4 v = na4[m * 4 + q];
            uint_t wsw[4] = { v.x, v.y, v.z, v.w };
#pragma unroll
            for (int u = 0; u < 4; ++u) {
                const float f0 = bf2f(wsw[u]);
                const float f1 = bfhi2f(wsw[u]);
                const int h = q * 8 + u * 2;
                s0 += xa0[h] * f0;     s1 += xa1[h] * f0;
                s0 += xa0[h + 1] * f1; s1 += xa1[h + 1] * f1;
            }
        }
        const float mk0 = mask[(n0 + r0) * NROWS + m];
        const float mk1 = mask[(n0 + r1) * NROWS + m];
        s0 *= mk0; s1 *= mk1;
        mx0 = fmaxf(mx0, s0); mx1 = fmaxf(mx1, s1);
        *(uint_t*)&pT[m * 8 + r0] = (uint_t)f2bf(s0) | ((uint_t)f2bf(s1) << 16);
    }
#pragma unroll
    for (int off = 32; off >= 1; off >>= 1) {
        mx0 = fmaxf(mx0, __shfl_xor(mx0, off));
        mx1 = fmaxf(mx1, __shfl_xor(mx1, off));
    }
    // exp + sum (lane-private LDS slots: no barrier needed within wave)
    float l0 = 0.f, l1 = 0.f;
    for (int it = 0; it < 32; ++it) {
        const int m = it * 64 + lane;
        const uint_t pv = *(const uint_t*)&pT[m * 8 + r0];
        const float e0 = __expf(bf2f(pv) - mx0);
        const float e1 = __expf(bfhi2f(pv) - mx1);
        l0 += e0; l1 += e1;
        *(uint_t*)&pT[m * 8 + r0] = (uint_t)f2bf(e0) | ((uint_t)f2bf(e1) << 16);
    }
#pragma unroll
    for (int off = 32; off >= 1; off >>= 1) {
        l0 += __shfl_xor(l0, off);
        l1 += __shfl_xor(l1, off);
    }
    if (lane == 0) { row_inv[r0] = 1.f / l0; row_inv[r1] = 1.f / l1; }
    __syncthreads();

    // ---- Phase 2: PV. thread = (kc = t>>5 m-chunk, dg = t&31 col-group of 8) ----
    const int kc = t >> 5, dg = t & 31, d0 = dg * 8;
    float acc[8][8];
#pragma unroll
    for (int i = 0; i < 8; ++i)
#pragma unroll
        for (int j = 0; j < 8; ++j) acc[i][j] = 0.f;

    {
        const int mbase = kc * 256;
#pragma unroll 2
        for (int mm = 0; mm < 256; ++mm) {
            const int m = mbase + mm;
            const uint4 pq = *(const uint4*)&pT[m * 8];
            float p_[8];
            p_[0] = bf2f(pq.x); p_[1] = bfhi2f(pq.x);
            p_[2] = bf2f(pq.y); p_[3] = bfhi2f(pq.y);
            p_[4] = bf2f(pq.z); p_[5] = bfhi2f(pq.z);
            p_[6] = bf2f(pq.w); p_[7] = bfhi2f(pq.w);
            const float4* nb4 = (const float4*)(neibs + m * DIN + d0);
            const float4 b0 = nb4[0], b1 = nb4[1];
#pragma unroll
            for (int r = 0; r < 8; ++r) {
                acc[r][0] += p_[r] * b0.x; acc[r][1] += p_[r] * b0.y;
                acc[r][2] += p_[r] * b0.z; acc[r][3] += p_[r] * b0.w;
                acc[r][4] += p_[r] * b1.x; acc[r][5] += p_[r] * b1.y;
                acc[r][6] += p_[r] * b1.z; acc[r][7] += p_[r] * b1.w;
            }
        }
    }

    float* red = (float*)pT;           // pT reads complete after reduce's barrier
    block_reduce_acc(red, kc, dg, acc);

    if (kc == 0) {
        float inv[8];
#pragma unroll
        for (int r2 = 0; r2 < 8; ++r2) inv[r2] = row_inv[r2];
#pragma unroll
        for (int j = 0; j < 8; ++j) {
            uint4 q;
            q.x = (uint_t)f2bf(sigm(acc[0][j] * inv[0])) | ((uint_t)f2bf(sigm(acc[1][j] * inv[1])) << 16);
            q.y = (uint_t)f2bf(sigm(acc[2][j] * inv[2])) | ((uint_t)f2bf(sigm(acc[3][j] * inv[3])) << 16);
            q.z = (uint_t)f2bf(sigm(acc[4][j] * inv[4])) | ((uint_t)f2bf(sigm(acc[5][j] * inv[5])) << 16);
            q.w = (uint_t)f2bf(sigm(acc[6][j] * inv[6])) | ((uint_t)f2bf(sigm(acc[7][j] * inv[7])) << 16);
            *(uint4*)&AT[(256 + d0 + j) * 8] = q;
        }
    }
    __syncthreads();

    // ---- Phase 3: FC. Same split-K structure, K = 512 ----
    float acc2[8][8];
#pragma unroll
    for (int i = 0; i < 8; ++i)
#pragma unroll
        for (int j = 0; j < 8; ++j) acc2[i][j] = 0.f;

    {
        const int kbase = kc * 64;
#pragma unroll 2
        for (int kk = 0; kk < 64; ++kk) {
            const int k = kbase + kk;
            const uint4 aq = *(const uint4*)&AT[k * 8];
            float a_[8];
            a_[0] = bf2f(aq.x); a_[1] = bfhi2f(aq.x);
            a_[2] = bf2f(aq.y); a_[3] = bfhi2f(aq.y);
            a_[4] = bf2f(aq.z); a_[5] = bfhi2f(aq.z);
            a_[6] = bf2f(aq.w); a_[7] = bfhi2f(aq.w);
            const float4* w4 = (const float4*)(fcx_w + k * DOUT + d0);
            const float4 b0 = w4[0], b1 = w4[1];
#pragma unroll
            for (int r = 0; r < 8; ++r) {
                acc2[r][0] += a_[r] * b0.x; acc2[r][1] += a_[r] * b0.y;
                acc2[r][2] += a_[r] * b0.z; acc2[r][3] += a_[r] * b0.w;
                acc2[r][4] += a_[r] * b1.x; acc2[r][5] += a_[r] * b1.y;
                acc2[r][6] += a_[r] * b1.z; acc2[r][7] += a_[r] * b1.w;
            }
        }
    }

    block_reduce_acc(red, kc, dg, acc2);

    if (kc == 0) {
        const float4 fb0 = *(const float4*)&fcx_b[d0];
        const float4 fb1 = *(const float4*)&fcx_b[d0 + 4];
        const float bia[8] = { fb0.x, fb0.y, fb0.z, fb0.w, fb1.x, fb1.y, fb1.z, fb1.w };
#pragma unroll
        for (int r2 = 0; r2 < 8; ++r2) {
            float4 o0, o1;
            o0.x = sigm(acc2[r2][0] + bia[0]); o0.y = sigm(acc2[r2][1] + bia[1]);
            o0.z = sigm(acc2[r2][2] + bia[2]); o0.w = sigm(acc2[r2][3] + bia[3]);
            o1.x = sigm(acc2[r2][4] + bia[4]); o1.y = sigm(acc2[r2][5] + bia[5]);
            o1.z = sigm(acc2[r2][6] + bia[6]); o1.w = sigm(acc2[r2][7] + bia[7]);
            *(float4*)&out[(n0 + r2) * DOUT + d0] = o0;
            *(float4*)&out[(n0 + r2) * DOUT + d0 + 4] = o1;
        }
    }
}

extern "C" void kernel_launch(void* const* d_in, const int* in_sizes, int n_in,
                              void* d_out, int out_size, void* d_ws, size_t ws_size,
                              hipStream_t stream) {
    const float* x      = (const float*)d_in[0];
    const float* neibs  = (const float*)d_in[1];
    // d_in[2] = edge_emb: dead code in the reference, intentionally unread.
    const float* mask   = (const float*)d_in[3];
    const float* ax_w1  = (const float*)d_in[4];
    const float* ax_b1  = (const float*)d_in[5];
    const float* ax_w2  = (const float*)d_in[6];
    const float* ax_b2  = (const float*)d_in[7];
    const float* an_w1  = (const float*)d_in[8];
    const float* an_b1  = (const float*)d_in[9];
    const float* an_w2  = (const float*)d_in[10];
    const float* an_b2  = (const float*)d_in[11];
    // d_in[12..15] = ae_* : dead code, unread.
    const float* fcx_w  = (const float*)d_in[16];
    const float* fcx_b  = (const float*)d_in[17];
    float* out = (float*)d_out;

    float*    x_att = (float*)d_ws;                          // 2048*32 fp32 = 256 KB
    ushort_t* n_att = (ushort_t*)(x_att + NROWS * DH);       // 2048*32 bf16 = 128 KB

    mlp_kernel<<<512, 256, 0, stream>>>(
        x, neibs, ax_w1, ax_b1, ax_w2, ax_b2,
        an_w1, an_b1, an_w2, an_b2, x_att, n_att);

    attn_kernel<<<256, 256, 0, stream>>>(
        x, neibs, mask, x_att, n_att, fcx_w, fcx_b, out);
}

// Round 3
// 410.969 us; speedup vs baseline: 1.4647x; 1.0824x over previous
//
#include <hip/hip_runtime.h>
#include <hip/hip_bf16.h>
#include <math.h>

#define NROWS 2048
#define DIN 256
#define DH 32
#define DOUT 256

typedef unsigned short ushort_t;
typedef unsigned int uint_t;
typedef __attribute__((ext_vector_type(8))) short short8;
typedef __attribute__((ext_vector_type(4))) float floatx4;

__device__ __forceinline__ float bf2f(uint_t u) {      // low 16 bits as bf16
    union { uint_t i; float f; } v; v.i = u << 16; return v.f;
}
__device__ __forceinline__ ushort_t f2bf(float f) {
    __hip_bfloat16 h = __float2bfloat16(f);
    union { __hip_bfloat16 h; ushort_t u; } v; v.h = h; return v.u;
}
__device__ __forceinline__ float sigm(float v) { return 1.0f / (1.0f + __expf(-v)); }

// LDS row strides (shorts). Byte stride must be 16-B aligned; dword stride
// chosen ≡ 12 (mod 32) so A-frag lanes (r,q) spread across banks.
#define PSTR 2072   // pTr: 8 rows x 2072 shorts = 33152 B
#define ASTR 536    // ATr: 8 rows x 536  shorts = 8576 B

// ---------------- Kernel 1: MLPs + bf16 B-fragment packing ----------------
// grid 832 x 256:
//   b <  256 : x      -> x_att (fp32)      (8 rows/block)
//   b <  512 : neibs  -> n_att (bf16)
//   b <  768 : neibs  -> B_pack  (bf16, MFMA-B fragment order, 1 MB)
//   b <  832 : fcx_w  -> W_pack  (bf16, MFMA-B fragment order, 256 KB)
// Fragment order: flat8group g = s*1024 + w*256 + t*64 + q*16 + n holds
// B[k = 32s+8q+j][ncol = 64w+16t+n], j=0..7 — so in the GEMM K-loop the 64
// lanes (q=lane>>4, n=lane&15) of wave w, tile t, step s read one contiguous
// 1 KB slab with lane-contiguous 16-B loads.
__global__ __launch_bounds__(256) void prep_kernel(
    const float* __restrict__ x, const float* __restrict__ neibs,
    const float* __restrict__ ax_w1, const float* __restrict__ ax_b1,
    const float* __restrict__ ax_w2, const float* __restrict__ ax_b2,
    const float* __restrict__ an_w1, const float* __restrict__ an_b1,
    const float* __restrict__ an_w2, const float* __restrict__ an_b2,
    const float* __restrict__ fcx_w,
    float* __restrict__ x_att, ushort_t* __restrict__ n_att,
    short8* __restrict__ B_pack, short8* __restrict__ W_pack)
{
    const int t = threadIdx.x;
    const int b = blockIdx.x;

    __shared__ float srow[8][DIN];
    __shared__ float hbuf[8][DH];

    if (b < 512) {
        const bool is_x = b < 256;
        const int row0 = (is_x ? b : b - 256) * 8;
        const float* __restrict__ in = is_x ? x : neibs;
        const float* __restrict__ w1 = is_x ? ax_w1 : an_w1;
        const float* __restrict__ b1 = is_x ? ax_b1 : an_b1;
        const float* __restrict__ w2 = is_x ? ax_w2 : an_w2;
        const float* __restrict__ b2 = is_x ? ax_b2 : an_b2;

        const int r = t >> 5, c = t & 31;
        {
            const float4* in4 = (const float4*)(in + (row0 + r) * DIN);
            float4 a = in4[c * 2], bb = in4[c * 2 + 1];
            *(float4*)&srow[r][c * 8] = a;
            *(float4*)&srow[r][c * 8 + 4] = bb;
        }
        __syncthreads();

        float s = b1[c];
#pragma unroll 8
        for (int k = 0; k < DIN; ++k) s += srow[r][k] * w1[k * DH + c];
        s = tanhf(s);
        hbuf[r][c] = s;
        __syncthreads();

        float s2 = b2[c];
#pragma unroll
        for (int j = 0; j < DH; ++j) s2 += hbuf[r][j] * w2[j * DH + c];

        if (is_x) x_att[(row0 + r) * DH + c] = s2;
        else      n_att[(row0 + r) * DH + c] = f2bf(s2);
    } else if (b < 768) {
        const int g = (b - 512) * 256 + t;
        const int n = g & 15, q = (g >> 4) & 3, tt = (g >> 6) & 3, w = (g >> 8) & 3;
        const int s = g >> 10;                       // 0..63
        const int ncol = w * 64 + tt * 16 + n;
        const int kb = 32 * s + 8 * q;
        short8 v;
#pragma unroll
        for (int j = 0; j < 8; ++j)
            v[j] = (short)f2bf(neibs[(size_t)(kb + j) * DIN + ncol]);
        B_pack[g] = v;
    } else {
        const int g = (b - 768) * 256 + t;
        const int n = g & 15, q = (g >> 4) & 3, tt = (g >> 6) & 3, w = (g >> 8) & 3;
        const int s = g >> 10;                       // 0..15
        const int ncol = w * 64 + tt * 16 + n;
        const int kb = 32 * s + 8 * q;
        short8 v;
#pragma unroll
        for (int j = 0; j < 8; ++j)
            v[j] = (short)f2bf(fcx_w[(size_t)(kb + j) * DOUT + ncol]);
        W_pack[g] = v;
    }
}

// ---------------- Kernel 2: fused scores/softmax + MFMA PV + MFMA FC ------
// 256 blocks x 256 threads; block = 8 target rows; wave w owns d-cols
// [64w, 64w+64) in the two GEMMs (4 tiles of 16).
__global__ __launch_bounds__(256) void attn_kernel(
    const float* __restrict__ x, const float* __restrict__ mask,
    const float* __restrict__ x_att, const ushort_t* __restrict__ n_att,
    const short8* __restrict__ B_pack, const short8* __restrict__ W_pack,
    const float* __restrict__ fcx_b, float* __restrict__ out)
{
    __shared__ __align__(16) ushort_t pTr[8 * PSTR];  // P bf16, row-major per target row
    __shared__ __align__(16) ushort_t ATr[8 * ASTR];  // [x|agg] bf16, row-major (K=512)
    __shared__ float row_inv[8];

    const int t = threadIdx.x;
    const int n0 = blockIdx.x * 8;
    const int wv = t >> 6, lane = t & 63;

    // ---- Phase 0: stage x rows into ATr (k = 0..255) ----
#pragma unroll
    for (int r = 0; r < 8; ++r)
        ATr[r * ASTR + t] = f2bf(x[(size_t)(n0 + r) * DIN + t]);

    // ---- Phase 1: scores. wave wv owns rows r0, r1; lanes sweep m ----
    const int r0 = 2 * wv, r1 = r0 + 1;
    float xa0[DH], xa1[DH];
#pragma unroll
    for (int h = 0; h < DH; ++h) {
        xa0[h] = x_att[(n0 + r0) * DH + h];
        xa1[h] = x_att[(n0 + r1) * DH + h];
    }
    float mx0 = -1e30f, mx1 = -1e30f;
    const uint4* na4 = (const uint4*)n_att;
    for (int it = 0; it < 32; ++it) {
        const int m = it * 64 + lane;
        float s0 = 0.f, s1 = 0.f;
#pragma unroll
        for (int qq = 0; qq < 4; ++qq) {
            uint4 v = na4[m * 4 + qq];
            uint_t wsw[4] = { v.x, v.y, v.z, v.w };
#pragma unroll
            for (int u = 0; u < 4; ++u) {
                const float f0 = bf2f(wsw[u] & 0xffffu);
                const float f1 = bf2f(wsw[u] >> 16);
                const int h = qq * 8 + u * 2;
                s0 += xa0[h] * f0;     s1 += xa1[h] * f0;
                s0 += xa0[h + 1] * f1; s1 += xa1[h + 1] * f1;
            }
        }
        s0 *= mask[(size_t)(n0 + r0) * NROWS + m];
        s1 *= mask[(size_t)(n0 + r1) * NROWS + m];
        mx0 = fmaxf(mx0, s0); mx1 = fmaxf(mx1, s1);
        pTr[r0 * PSTR + m] = f2bf(s0);
        pTr[r1 * PSTR + m] = f2bf(s1);
    }
#pragma unroll
    for (int off = 32; off >= 1; off >>= 1) {
        mx0 = fmaxf(mx0, __shfl_xor(mx0, off));
        mx1 = fmaxf(mx1, __shfl_xor(mx1, off));
    }
    float l0 = 0.f, l1 = 0.f;
    for (int it = 0; it < 32; ++it) {
        const int m = it * 64 + lane;
        const float e0 = __expf(bf2f(pTr[r0 * PSTR + m]) - mx0);
        const float e1 = __expf(bf2f(pTr[r1 * PSTR + m]) - mx1);
        l0 += e0; l1 += e1;
        pTr[r0 * PSTR + m] = f2bf(e0);
        pTr[r1 * PSTR + m] = f2bf(e1);
    }
#pragma unroll
    for (int off = 32; off >= 1; off >>= 1) {
        l0 += __shfl_xor(l0, off);
        l1 += __shfl_xor(l1, off);
    }
    if (lane == 0) { row_inv[r0] = 1.f / l0; row_inv[r1] = 1.f / l1; }
    __syncthreads();

    // ---- Phase 2: PV via MFMA. A = P (rows dup'd to 16), B = B_pack ----
    const int q = lane >> 4;          // 0..3 -> k-offset q*8
    const int ar = lane & 7;          // A row (rows 8-15 duplicate 0-7)
    const char* aBase = (const char*)pTr + ar * (PSTR * 2) + q * 16;

    floatx4 acc[4];
#pragma unroll
    for (int tt = 0; tt < 4; ++tt) acc[tt] = (floatx4){0.f, 0.f, 0.f, 0.f};

    for (int s = 0; s < 64; ++s) {
        const short8 av = *(const short8*)(aBase + s * 64);
#pragma unroll
        for (int tt = 0; tt < 4; ++tt) {
            const int slab = (s * 4 + wv) * 4 + tt;
            const short8 bv = B_pack[slab * 64 + lane];
            acc[tt] = __builtin_amdgcn_mfma_f32_16x16x32_bf16(av, bv, acc[tt], 0, 0, 0);
        }
    }
    // epilogue: C rows 0-7 live in lanes 0-31 (row=(lane>>4)*4+reg, col=lane&15)
    if (lane < 32) {
        const int col = lane & 15;
        const int rbase = (lane >> 4) * 4;
#pragma unroll
        for (int tt = 0; tt < 4; ++tt) {
            const int n = wv * 64 + tt * 16 + col;
#pragma unroll
            for (int rg = 0; rg < 4; ++rg) {
                const int row = rbase + rg;
                ATr[row * ASTR + 256 + n] = f2bf(sigm(acc[tt][rg] * row_inv[row]));
            }
        }
    }
    __syncthreads();

    // ---- Phase 3: FC via MFMA. A = [x|agg] (K=512), B = W_pack ----
    floatx4 acc2[4];
#pragma unroll
    for (int tt = 0; tt < 4; ++tt) acc2[tt] = (floatx4){0.f, 0.f, 0.f, 0.f};

    const char* a2Base = (const char*)ATr + ar * (ASTR * 2) + q * 16;
    for (int s = 0; s < 16; ++s) {
        const short8 av = *(const short8*)(a2Base + s * 64);
#pragma unroll
        for (int tt = 0; tt < 4; ++tt) {
            const int slab = (s * 4 + wv) * 4 + tt;
            const short8 bv = W_pack[slab * 64 + lane];
            acc2[tt] = __builtin_amdgcn_mfma_f32_16x16x32_bf16(av, bv, acc2[tt], 0, 0, 0);
        }
    }
    if (lane < 32) {
        const int col = lane & 15;
        const int rbase = (lane >> 4) * 4;
#pragma unroll
        for (int tt = 0; tt < 4; ++tt) {
            const int n = wv * 64 + tt * 16 + col;
            const float bias = fcx_b[n];
#pragma unroll
            for (int rg = 0; rg < 4; ++rg) {
                const int row = rbase + rg;
                out[(size_t)(n0 + row) * DOUT + n] = sigm(acc2[tt][rg] + bias);
            }
        }
    }
}

extern "C" void kernel_launch(void* const* d_in, const int* in_sizes, int n_in,
                              void* d_out, int out_size, void* d_ws, size_t ws_size,
                              hipStream_t stream) {
    const float* x      = (const float*)d_in[0];
    const float* neibs  = (const float*)d_in[1];
    // d_in[2] = edge_emb: dead code in the reference, intentionally unread.
    const float* mask   = (const float*)d_in[3];
    const float* ax_w1  = (const float*)d_in[4];
    const float* ax_b1  = (const float*)d_in[5];
    const float* ax_w2  = (const float*)d_in[6];
    const float* ax_b2  = (const float*)d_in[7];
    const float* an_w1  = (const float*)d_in[8];
    const float* an_b1  = (const float*)d_in[9];
    const float* an_w2  = (const float*)d_in[10];
    const float* an_b2  = (const float*)d_in[11];
    // d_in[12..15] = ae_* : dead code, unread.
    const float* fcx_w  = (const float*)d_in[16];
    const float* fcx_b  = (const float*)d_in[17];
    float* out = (float*)d_out;

    char* ws = (char*)d_ws;
    float*    x_att  = (float*)ws;                       // 256 KB
    ushort_t* n_att  = (ushort_t*)(ws + 262144);         // 128 KB
    short8*   B_pack = (short8*)(ws + 393216);           // 1 MB
    short8*   W_pack = (short8*)(ws + 1441792);          // 256 KB

    prep_kernel<<<832, 256, 0, stream>>>(
        x, neibs, ax_w1, ax_b1, ax_w2, ax_b2,
        an_w1, an_b1, an_w2, an_b2, fcx_w,
        x_att, n_att, B_pack, W_pack);

    attn_kernel<<<256, 256, 0, stream>>>(
        x, mask, x_att, n_att, B_pack, W_pack, fcx_b, out);
}

// Round 4
// 384.140 us; speedup vs baseline: 1.5670x; 1.0698x over previous
//
#include <hip/hip_runtime.h>
#include <hip/hip_bf16.h>
#include <math.h>

#define NROWS 2048
#define DIN 256
#define DH 32
#define DOUT 256

typedef unsigned short ushort_t;
typedef unsigned int uint_t;
typedef __attribute__((ext_vector_type(8))) short short8;
typedef __attribute__((ext_vector_type(4))) float floatx4;

__device__ __forceinline__ float bf2f(uint_t u) {
    union { uint_t i; float f; } v; v.i = u << 16; return v.f;
}
__device__ __forceinline__ ushort_t f2bf(float f) {
    __hip_bfloat16 h = __float2bfloat16(f);
    union { __hip_bfloat16 h; ushort_t u; } v; v.h = h; return v.u;
}
__device__ __forceinline__ float sigm(float v) { return 1.0f / (1.0f + __expf(-v)); }

// LDS strides in shorts; byte strides are 16-B multiples.
#define PSTR 2056   // 8 rows x 2056 shorts = 32896 B (P, bf16)
#define ASTR 520    // 8 rows x 520 shorts  =  8320 B ([x|agg], bf16)

// ---------------- Kernel 1: MLPs + B-fragment packing ----------------
// grid 592 x 256:
//   b <  256 : x MLP     -> x_attB (bf16 row-major, A-frag friendly)
//   b <  512 : neibs MLP -> n_attP (bf16, MFMA-B fragment order for scores)
//   b <  576 : neibs     -> B_pack (bf16 B-frag order, LDS-transposed, 1 MB)
//   b <  592 : fcx_w     -> W_pack (bf16 B-frag order, 256 KB)
// B-frag order (16x16x32): group g = s*1024 + w*256 + tt*64 + q*16 + n holds
// B[k=32s+8q+j][col=64w+16tt+n], j=0..7: in the GEMM loop wave w/tile tt/step s
// reads one contiguous 1 KB slab with lane-contiguous 16-B loads.
__global__ __launch_bounds__(256) void prep_kernel(
    const float* __restrict__ x, const float* __restrict__ neibs,
    const float* __restrict__ ax_w1, const float* __restrict__ ax_b1,
    const float* __restrict__ ax_w2, const float* __restrict__ ax_b2,
    const float* __restrict__ an_w1, const float* __restrict__ an_b1,
    const float* __restrict__ an_w2, const float* __restrict__ an_b2,
    const float* __restrict__ fcx_w,
    ushort_t* __restrict__ x_attB, short8* __restrict__ n_attP,
    short8* __restrict__ B_pack, short8* __restrict__ W_pack)
{
    __shared__ float smem[32 * 256];   // 32 KB, reused per branch
    const int t = threadIdx.x;
    const int b = blockIdx.x;

    if (b < 512) {
        float (*srow)[DIN] = (float (*)[DIN])smem;      // 8x256
        float* hbuf = smem + 8 * DIN;                   // 8x32
        float* sbuf = smem + 8 * DIN + 8 * DH;          // 8x32

        const bool is_x = b < 256;
        const int row0 = (is_x ? b : b - 256) * 8;
        const float* __restrict__ in = is_x ? x : neibs;
        const float* __restrict__ w1 = is_x ? ax_w1 : an_w1;
        const float* __restrict__ b1 = is_x ? ax_b1 : an_b1;
        const float* __restrict__ w2 = is_x ? ax_w2 : an_w2;
        const float* __restrict__ b2 = is_x ? ax_b2 : an_b2;

        const int r = t >> 5, c = t & 31;
        {
            const float4* in4 = (const float4*)(in + (size_t)(row0 + r) * DIN);
            float4 a = in4[c * 2], bb = in4[c * 2 + 1];
            *(float4*)&srow[r][c * 8] = a;
            *(float4*)&srow[r][c * 8 + 4] = bb;
        }
        __syncthreads();

        float s = b1[c];
#pragma unroll 8
        for (int k = 0; k < DIN; ++k) s += srow[r][k] * w1[k * DH + c];
        s = tanhf(s);
        hbuf[r * DH + c] = s;
        __syncthreads();

        float s2 = b2[c];
#pragma unroll
        for (int j = 0; j < DH; ++j) s2 += hbuf[r * DH + j] * w2[j * DH + c];

        if (is_x) {
            x_attB[(size_t)(row0 + r) * DH + c] = f2bf(s2);
        } else {
            sbuf[r * DH + c] = s2;
            __syncthreads();
            if (t < 32) {
                const int r2 = t >> 2, q = t & 3;
                const int row = row0 + r2;
                short8 v;
#pragma unroll
                for (int j = 0; j < 8; ++j) v[j] = (short)f2bf(sbuf[r2 * DH + q * 8 + j]);
                n_attP[(row >> 4) * 64 + q * 16 + (row & 15)] = v;
            }
        }
    } else if (b < 576) {
        // B_pack: slab s of 32 k-rows x 256 cols, LDS transpose.
        const int s = b - 512;                           // 0..63
        float* tile = smem;                              // [32][256]
#pragma unroll
        for (int i = 0; i < 8; ++i) {
            const int e = i * 256 + t;                   // float4 index
            const int row = e >> 6, c4 = e & 63;
            const float4 v = ((const float4*)neibs)[(size_t)(32 * s + row) * 64 + c4];
            *(float4*)&tile[row * 256 + c4 * 4] = v;
        }
        __syncthreads();
#pragma unroll
        for (int i = 0; i < 4; ++i) {
            const int G = i * 256 + t;                   // 0..1023
            const int n = G & 15, q = (G >> 4) & 3, tt = (G >> 6) & 3, w = G >> 8;
            const int col = w * 64 + tt * 16 + n;
            short8 v;
#pragma unroll
            for (int j = 0; j < 8; ++j) v[j] = (short)f2bf(tile[(8 * q + j) * 256 + col]);
            B_pack[s * 1024 + G] = v;
        }
    } else {
        // W_pack: same, source fcx_w (512x256), 16 slabs.
        const int s = b - 576;                           // 0..15
        float* tile = smem;
#pragma unroll
        for (int i = 0; i < 8; ++i) {
            const int e = i * 256 + t;
            const int row = e >> 6, c4 = e & 63;
            const float4 v = ((const float4*)fcx_w)[(size_t)(32 * s + row) * 64 + c4];
            *(float4*)&tile[row * 256 + c4 * 4] = v;
        }
        __syncthreads();
#pragma unroll
        for (int i = 0; i < 4; ++i) {
            const int G = i * 256 + t;
            const int n = G & 15, q = (G >> 4) & 3, tt = (G >> 6) & 3, w = G >> 8;
            const int col = w * 64 + tt * 16 + n;
            short8 v;
#pragma unroll
            for (int j = 0; j < 8; ++j) v[j] = (short)f2bf(tile[(8 * q + j) * 256 + col]);
            W_pack[s * 1024 + G] = v;
        }
    }
}

// ---------------- Kernel 2: MFMA scores + softmax + MFMA PV + MFMA FC ----
// 256 blocks x 512 threads (8 waves = 2/SIMD); block = 8 target rows.
// PV/FC: wave w -> col-group cq=w&3 (64 cols), K-half kh=w>>2; LDS reduce.
__global__ __launch_bounds__(512, 2) void attn_kernel(
    const float* __restrict__ x, const float* __restrict__ mask,
    const ushort_t* __restrict__ x_attB, const short8* __restrict__ n_attP,
    const short8* __restrict__ B_pack, const short8* __restrict__ W_pack,
    const float* __restrict__ fcx_b, float* __restrict__ out)
{
    __shared__ __align__(16) ushort_t pTr[8 * PSTR];   // 32.9 KB
    __shared__ __align__(16) ushort_t ATr[8 * ASTR];   // 8.3 KB
    __shared__ float row_inv[8];

    const int t = threadIdx.x;
    const int n0 = blockIdx.x * 8;
    const int w = t >> 6, lane = t & 63;
    const int q = lane >> 4, nn = lane & 15;
    const int arow = lane & 7;                 // A row (rows 8-15 duplicate 0-7)
    const int rbase = (lane >> 4) * 4;         // C row base (lanes>=32 duplicate)

    // ---- Phase 0: stage x rows into ATr cols 0..255 (bf16) ----
#pragma unroll
    for (int i = 0; i < 4; ++i) {
        const int e = i * 512 + t;
        const int r = e >> 8, k = e & 255;
        ATr[r * ASTR + k] = f2bf(x[(size_t)(n0 + r) * DIN + k]);
    }

    // ---- Phase 1: scores via MFMA (K=32, one MFMA per 16-col tile) ----
    const short8 av_s = *(const short8*)(x_attB + (size_t)(n0 + arow) * DH + q * 8);
#pragma unroll 4
    for (int i = 0; i < 16; ++i) {
        const int tl = w * 16 + i;
        const short8 bv = n_attP[tl * 64 + lane];
        floatx4 c = __builtin_amdgcn_mfma_f32_16x16x32_bf16(
            av_s, bv, (floatx4){0.f, 0.f, 0.f, 0.f}, 0, 0, 0);
        if (lane < 32) {
            const int m = tl * 16 + nn;
#pragma unroll
            for (int rg = 0; rg < 4; ++rg) {
                const int row = rbase + rg;            // 0..7
                const float sv = c[rg] * mask[(size_t)(n0 + row) * NROWS + m];
                pTr[row * PSTR + m] = f2bf(sv);
            }
        }
    }
    __syncthreads();

    // ---- Phase 1b: softmax, wave w -> row w. b32 LDS ops (conflict-free) ----
    {
        ushort_t* prow = pTr + w * PSTR;
        uint_t raw[16];
        float mx = -1e30f;
#pragma unroll
        for (int j = 0; j < 16; ++j) {
            raw[j] = *(const uint_t*)(prow + j * 128 + 2 * lane);
            mx = fmaxf(mx, fmaxf(bf2f(raw[j] & 0xffffu), bf2f(raw[j] >> 16)));
        }
#pragma unroll
        for (int off = 32; off >= 1; off >>= 1) mx = fmaxf(mx, __shfl_xor(mx, off));
        float sum = 0.f;
#pragma unroll
        for (int j = 0; j < 16; ++j) {
            const float e0 = __expf(bf2f(raw[j] & 0xffffu) - mx);
            const float e1 = __expf(bf2f(raw[j] >> 16) - mx);
            sum += e0 + e1;
            *(uint_t*)(prow + j * 128 + 2 * lane) =
                (uint_t)f2bf(e0) | ((uint_t)f2bf(e1) << 16);
        }
#pragma unroll
        for (int off = 32; off >= 1; off >>= 1) sum += __shfl_xor(sum, off);
        if (lane == 0) row_inv[w] = 1.f / sum;
    }
    __syncthreads();

    // ---- Phase 2: PV. wave w: cols cq*64..+64, K-half kh (32 of 64 slabs) ----
    const int cq = w & 3, kh = w >> 2;
    const char* aBase = (const char*)pTr + arow * (PSTR * 2);
    floatx4 acc[4];
#pragma unroll
    for (int tt = 0; tt < 4; ++tt) acc[tt] = (floatx4){0.f, 0.f, 0.f, 0.f};

#pragma unroll 4
    for (int si = 0; si < 32; ++si) {
        const int s = kh * 32 + si;
        const short8 av = *(const short8*)(aBase + s * 64 + q * 16);
#pragma unroll
        for (int tt = 0; tt < 4; ++tt) {
            const short8 bv = B_pack[(s * 16 + cq * 4 + tt) * 64 + lane];
            acc[tt] = __builtin_amdgcn_mfma_f32_16x16x32_bf16(av, bv, acc[tt], 0, 0, 0);
        }
    }
    __syncthreads();                              // pTr reads done; safe to alias
    float* red = (float*)pTr;                     // 16 KB reduction buffer
    if (kh == 1) {
#pragma unroll
        for (int tt = 0; tt < 4; ++tt)
            *(floatx4*)&red[((cq * 4 + tt) * 64 + lane) * 4] = acc[tt];
    }
    __syncthreads();
    if (kh == 0) {
#pragma unroll
        for (int tt = 0; tt < 4; ++tt) {
            const floatx4 rv = *(const floatx4*)&red[((cq * 4 + tt) * 64 + lane) * 4];
            acc[tt] += rv;
        }
        if (lane < 32) {
#pragma unroll
            for (int tt = 0; tt < 4; ++tt) {
                const int n = cq * 64 + tt * 16 + nn;
#pragma unroll
                for (int rg = 0; rg < 4; ++rg) {
                    const int row = rbase + rg;
                    ATr[row * ASTR + 256 + n] = f2bf(sigm(acc[tt][rg] * row_inv[row]));
                }
            }
        }
    }
    __syncthreads();

    // ---- Phase 3: FC. K=512 (16 slabs), same split ----
    const char* a2 = (const char*)ATr + arow * (ASTR * 2);
    floatx4 acc2[4];
#pragma unroll
    for (int tt = 0; tt < 4; ++tt) acc2[tt] = (floatx4){0.f, 0.f, 0.f, 0.f};

#pragma unroll
    for (int si = 0; si < 8; ++si) {
        const int s = kh * 8 + si;
        const short8 av = *(const short8*)(a2 + s * 64 + q * 16);
#pragma unroll
        for (int tt = 0; tt < 4; ++tt) {
            const short8 bv = W_pack[(s * 16 + cq * 4 + tt) * 64 + lane];
            acc2[tt] = __builtin_amdgcn_mfma_f32_16x16x32_bf16(av, bv, acc2[tt], 0, 0, 0);
        }
    }
    __syncthreads();                              // red reuse
    if (kh == 1) {
#pragma unroll
        for (int tt = 0; tt < 4; ++tt)
            *(floatx4*)&red[((cq * 4 + tt) * 64 + lane) * 4] = acc2[tt];
    }
    __syncthreads();
    if (kh == 0) {
#pragma unroll
        for (int tt = 0; tt < 4; ++tt) {
            const floatx4 rv = *(const floatx4*)&red[((cq * 4 + tt) * 64 + lane) * 4];
            acc2[tt] += rv;
        }
        if (lane < 32) {
#pragma unroll
            for (int tt = 0; tt < 4; ++tt) {
                const int n = cq * 64 + tt * 16 + nn;
                const float bias = fcx_b[n];
#pragma unroll
                for (int rg = 0; rg < 4; ++rg) {
                    const int row = rbase + rg;
                    out[(size_t)(n0 + row) * DOUT + n] = sigm(acc2[tt][rg] + bias);
                }
            }
        }
    }
}

extern "C" void kernel_launch(void* const* d_in, const int* in_sizes, int n_in,
                              void* d_out, int out_size, void* d_ws, size_t ws_size,
                              hipStream_t stream) {
    const float* x      = (const float*)d_in[0];
    const float* neibs  = (const float*)d_in[1];
    // d_in[2] = edge_emb: dead code in the reference, intentionally unread.
    const float* mask   = (const float*)d_in[3];
    const float* ax_w1  = (const float*)d_in[4];
    const float* ax_b1  = (const float*)d_in[5];
    const float* ax_w2  = (const float*)d_in[6];
    const float* ax_b2  = (const float*)d_in[7];
    const float* an_w1  = (const float*)d_in[8];
    const float* an_b1  = (const float*)d_in[9];
    const float* an_w2  = (const float*)d_in[10];
    const float* an_b2  = (const float*)d_in[11];
    // d_in[12..15] = ae_* : dead code, unread.
    const float* fcx_w  = (const float*)d_in[16];
    const float* fcx_b  = (const float*)d_in[17];
    float* out = (float*)d_out;

    char* ws = (char*)d_ws;
    ushort_t* x_attB = (ushort_t*)ws;                    // 128 KB
    short8*   n_attP = (short8*)(ws + 131072);           // 128 KB
    short8*   B_pack = (short8*)(ws + 262144);           // 1 MB
    short8*   W_pack = (short8*)(ws + 1310720);          // 256 KB

    prep_kernel<<<592, 256, 0, stream>>>(
        x, neibs, ax_w1, ax_b1, ax_w2, ax_b2,
        an_w1, an_b1, an_w2, an_b2, fcx_w,
        x_attB, n_attP, B_pack, W_pack);

    attn_kernel<<<256, 512, 0, stream>>>(
        x, mask, x_attB, n_attP, B_pack, W_pack, fcx_b, out);
}